// Round 1
// baseline (2042.416 us; speedup 1.0000x reference)
//
#include <hip/hip_runtime.h>
#include <stdint.h>

#define B_   128
#define T_   64
#define E_   300
#define EPAD 384
#define H_   2048
#define G4   8192

typedef unsigned short u16;
typedef short bf8 __attribute__((ext_vector_type(8)));
typedef float f4 __attribute__((ext_vector_type(4)));

__device__ __forceinline__ u16 f2b(float f) {
    uint32_t u = __float_as_uint(f);
    u += 0x7fffu + ((u >> 16) & 1u);   // round-to-nearest-even
    return (u16)(u >> 16);
}
__device__ __forceinline__ float b2f(u16 s) {
    return __uint_as_float(((uint32_t)s) << 16);
}
__device__ __forceinline__ float sigm(float x) { return 1.f / (1.f + __expf(-x)); }
__device__ __forceinline__ float tanh_(float x) {
    float xx = fminf(fmaxf(x, -15.f), 15.f);
    float e = __expf(2.f * xx);
    return (e - 1.f) / (e + 1.f);
}

// ---- prep: weight conversion + zero-init ----
__global__ void prep_kernel(const float* __restrict__ w_hh, const float* __restrict__ w_ih,
                            const float* __restrict__ b_ih, const float* __restrict__ b_hh,
                            u16* __restrict__ w_hh_b, u16* __restrict__ w_ih_b,
                            float* __restrict__ bsum, float* __restrict__ c,
                            u16* __restrict__ h_b0) {
    int tid = blockIdx.x * blockDim.x + threadIdx.x;
    int np = gridDim.x * blockDim.x;
    for (int i = tid; i < G4 * H_; i += np) w_hh_b[i] = f2b(w_hh[i]);
    for (int i = tid; i < G4 * EPAD; i += np) {
        int n = i / EPAD, k = i - n * EPAD;
        w_ih_b[i] = (k < E_) ? f2b(w_ih[n * E_ + k]) : (u16)0;
    }
    for (int i = tid; i < G4; i += np) bsum[i] = b_ih[i] + b_hh[i];
    for (int i = tid; i < B_ * H_; i += np) c[i] = 0.f;
    for (int i = tid; i < B_ * H_; i += np) h_b0[i] = 0;
}

// ---- embedding gather -> bf16 padded rows [t*B+b][EPAD] ----
__global__ void gather_kernel(const int* __restrict__ input, const float* __restrict__ embed,
                              u16* __restrict__ x_b) {
    int r = blockIdx.x;                 // r = t*B + b
    int t = r >> 7, b = r & 127;
    int row = input[b * T_ + t];
    const float* src = embed + (size_t)row * E_;
    u16* dst = x_b + (size_t)r * EPAD;
    for (int e = threadIdx.x; e < EPAD; e += blockDim.x)
        dst[e] = (e < E_) ? f2b(src[e]) : (u16)0;
}

// ---- one LSTM time step, fused GEMM (K = 2048 h-part + 384 x-part) + cell ----
// grid (H/16, 2), block 512: WG covers 64 batch rows x 16 hidden cols x 4 gates.
// wave w: gate = w&3, m-half = w>>2 (2 m-tiles of 16).
__global__ __launch_bounds__(512) void
step_kernel(const u16* __restrict__ x_t,      // x_b + t*B*EPAD
            const u16* __restrict__ w_hh_b,   // [G4][H] bf16
            const u16* __restrict__ w_ih_b,   // [G4][EPAD] bf16
            const float* __restrict__ bsum,   // [G4]
            const u16* __restrict__ h_in,     // [B][H] bf16
            float* __restrict__ c_io,         // [B][H] fp32 in-place
            u16* __restrict__ h_out_b,        // [B][H] bf16
            float* __restrict__ h_out_f) {    // nullptr except last step
    __shared__ u16 Asl[64 * 136];             // 64 rows x 128 k, stride 136 (16B-aligned, padded)
    float* gbuf = (float*)Asl;                // overlay: [4][64][17] fp32 = 17408 B exact
    int tid = threadIdx.x;
    int wid = tid >> 6, lane = tid & 63;
    int gate = wid & 3, mh = wid >> 2;
    int q = lane >> 4, l16 = lane & 15;
    int j0 = blockIdx.x * 16;
    int mb = blockIdx.y * 64;
    int nrow = gate * H_ + j0 + l16;
    const u16* wh = w_hh_b + (size_t)nrow * H_;
    const u16* wi = w_ih_b + (size_t)nrow * EPAD;
    f4 acc[2] = {};
    for (int kc = 0; kc < 19; ++kc) {         // 16 chunks of h (2048) + 3 chunks of x (384)
        int k0 = kc * 128;
        for (int i = 0; i < 2; ++i) {         // stage A slab [64][128], coalesced 16B loads
            int idx = tid + i * 512;
            int row = idx >> 4, col = (idx & 15) << 3;
            bf8 v;
            if (kc < 16)
                v = *(const bf8*)&h_in[(size_t)(mb + row) * H_ + k0 + col];
            else
                v = *(const bf8*)&x_t[(size_t)(mb + row) * EPAD + (k0 - 2048) + col];
            *(bf8*)&Asl[row * 136 + col] = v;
        }
        __syncthreads();
        const u16* wr = (kc < 16) ? (wh + k0) : (wi + (k0 - 2048));
        for (int sub = 0; sub < 4; ++sub) {
            int ks = sub * 32 + q * 8;
            bf8 bfr = *(const bf8*)&wr[ks];   // B-frag: w row, contiguous k
            for (int at = 0; at < 2; ++at) {
                bf8 afr = *(const bf8*)&Asl[(mh * 32 + at * 16 + l16) * 136 + ks];
                acc[at] = __builtin_amdgcn_mfma_f32_16x16x32_bf16(afr, bfr, acc[at], 0, 0, 0);
            }
        }
        __syncthreads();
    }
    // gate exchange: each wave deposits its gate tile (C/D layout: row=q*4+r, col=l16)
    for (int at = 0; at < 2; ++at)
        for (int r = 0; r < 4; ++r) {
            int ml = mh * 32 + at * 16 + q * 4 + r;
            gbuf[(gate * 64 + ml) * 17 + l16] = acc[at][r];
        }
    __syncthreads();
    // fused LSTM cell: 64x16 = 1024 cells over 512 threads
    for (int i = 0; i < 2; ++i) {
        int idx = tid + i * 512;
        int ml = idx >> 4, jl = idx & 15;
        int m = mb + ml, j = j0 + jl;
        float gi = gbuf[(0 * 64 + ml) * 17 + jl] + bsum[j];
        float gf = gbuf[(1 * 64 + ml) * 17 + jl] + bsum[H_ + j];
        float gg = gbuf[(2 * 64 + ml) * 17 + jl] + bsum[2 * H_ + j];
        float go = gbuf[(3 * 64 + ml) * 17 + jl] + bsum[3 * H_ + j];
        float iv = sigm(gi), fv = sigm(gf), ov = sigm(go);
        float gv = tanh_(gg);
        size_t ci = (size_t)m * H_ + j;
        float cn = fv * c_io[ci] + iv * gv;
        c_io[ci] = cn;
        float hn = ov * tanh_(cn);
        if (h_out_f) h_out_f[ci] = hn;
        h_out_b[ci] = f2b(hn);
    }
}

extern "C" void kernel_launch(void* const* d_in, const int* in_sizes, int n_in,
                              void* d_out, int out_size, void* d_ws, size_t ws_size,
                              hipStream_t stream) {
    const int*   input = (const int*)d_in[0];
    const float* embed = (const float*)d_in[1];
    const float* w_ih  = (const float*)d_in[2];
    const float* w_hh  = (const float*)d_in[3];
    const float* b_ih  = (const float*)d_in[4];
    const float* b_hh  = (const float*)d_in[5];
    float* out = (float*)d_out;

    char* ws = (char*)d_ws;
    size_t o = 0;
    u16* w_hh_b = (u16*)(ws + o); o += (size_t)G4 * H_ * 2;        // 33.5 MB
    u16* w_ih_b = (u16*)(ws + o); o += (size_t)G4 * EPAD * 2;      // 6.3 MB
    u16* x_b    = (u16*)(ws + o); o += (size_t)B_ * T_ * EPAD * 2; // 6.3 MB
    float* bsum = (float*)(ws + o); o += (size_t)G4 * 4;
    float* c    = (float*)(ws + o); o += (size_t)B_ * H_ * 4;
    u16* h_b0   = (u16*)(ws + o); o += (size_t)B_ * H_ * 2;
    u16* h_b1   = (u16*)(ws + o); o += (size_t)B_ * H_ * 2;        // total ~48 MB

    prep_kernel<<<1024, 256, 0, stream>>>(w_hh, w_ih, b_ih, b_hh,
                                          w_hh_b, w_ih_b, bsum, c, h_b0);
    gather_kernel<<<B_ * T_, 64, 0, stream>>>(input, embed, x_b);

    for (int t = 0; t < T_; ++t) {
        const u16* hin = (t & 1) ? h_b1 : h_b0;
        u16* hob       = (t & 1) ? h_b0 : h_b1;
        float* hof     = (t == T_ - 1) ? out : nullptr;
        step_kernel<<<dim3(H_ / 16, 2), 512, 0, stream>>>(
            x_b + (size_t)t * B_ * EPAD, w_hh_b, w_ih_b, bsum, hin, c, hob, hof);
    }
}